// Round 14
// baseline (72.547 us; speedup 1.0000x reference)
//
#include <hip/hip_runtime.h>
#include <math.h>

#define IMG_H 512
#define IMG_W 512
#define CH    3
#define TILE_W 16
#define TILE_H 32                // two 16-row halves
#define HALF  16
#define PAD   2
#define TP    20                 // padded per-half tile: 20 rows x 20 cols

typedef float v2f __attribute__((ext_vector_type(2)));
typedef float v4f __attribute__((ext_vector_type(4)));

#if __has_builtin(__builtin_amdgcn_exp2f)
#define EXP2(x) __builtin_amdgcn_exp2f(x)
#else
#define EXP2(x) exp2f(x)
#endif

#if __has_builtin(__builtin_amdgcn_rcpf)
#define RCP(x) __builtin_amdgcn_rcpf(x)
#else
#define RCP(x) (1.0f / (x))
#endif

#define LOV(a) __builtin_shufflevector(a, a, 0, 1)
#define HIV(a) __builtin_shufflevector(a, a, 2, 3)

__device__ __forceinline__ int reflect_idx(int i, int n) {
    i = (i < 0) ? -i : i;
    i = (i >= n) ? (2 * n - 2 - i) : i;
    return i;
}

__global__ __launch_bounds__(128)
void bilateral_kernel(const float* __restrict__ in, float* __restrict__ out) {
    // 4 px/thread: rows (r0, r0+1) in halves A and B (=A+16), same column.
    // Channels interleaved across halves so every v2f is a natural VGPR pair:
    //   planeP[r][c] = (xA, xB, yA, yB)   planeQ[r][c] = (zA, zB, wA, wB)
    // 6-row x 5-col window serves both row-centers -> 16 b128/px (was 26).
    // 20x20-float4, wave lane-groups on rows 4 apart: proven conflict-free.
    // sched_barrier(0) fences (2 per window row) stop the load hoisting that
    // blew VGPR to 124/112/132 in R3/R7/R13.
    __shared__ v4f planeP[TP][TP];
    __shared__ v4f planeQ[TP][TP];

    const float S = sqrtf(312.5f * 1.44269504088896f);  // compile-time folded

    const int b  = blockIdx.z;
    const int by = blockIdx.y * TILE_H;
    const int bx = blockIdx.x * TILE_W;
    const int tx = threadIdx.x;
    const int ty = threadIdx.y;          // 0..7: one row pair per half
    const int tid = ty * TILE_W + tx;

    // Staging: 400 entries, each covers two pixels (padded rows r and r+16).
    for (int i = tid; i < TP * TP; i += TILE_W * 8) {
        const int r  = i / TP;
        const int cc = i - r * TP;
        const int gyA = reflect_idx(by + r - PAD, IMG_H);
        const int gyB = reflect_idx(by + HALF + r - PAD, IMG_H);
        const int gx  = reflect_idx(bx + cc - PAD, IMG_W);
        const float* pA = in + ((size_t)(b * IMG_H + gyA) * IMG_W + gx) * CH;
        const float* pB = in + ((size_t)(b * IMG_H + gyB) * IMG_W + gx) * CH;
        const float a0 = pA[0] * S, a1 = pA[1] * S, a2 = pA[2] * S;
        const float e0 = pB[0] * S, e1 = pB[1] * S, e2 = pB[2] * S;
        const float wA = -fmaf(a0, a0, fmaf(a1, a1, a2 * a2));
        const float wB = -fmaf(e0, e0, fmaf(e1, e1, e2 * e2));
        planeP[r][cc] = (v4f){ a0, e0, a1, e1 };
        planeQ[r][cc] = (v4f){ a2, e2, wA, wB };
    }
    __syncthreads();

    // Row-pair permutation: wave 0 (ty 0..3) -> r0 {0,4,8,12}; wave 1 -> {2,6,10,14}.
    const int r0 = ((ty & 3) << 2) | ((ty >> 2) << 1);

    // Spatial gaussian products (normalized), index [min(dy,4-dy)][min(dx,4-dx)].
    // Applied OUTSIDE the exponent: w = WK * exp2(t)  (WK = literal).
    const float WKT[3][3] = {
        { 0.00296911f, 0.01330370f, 0.02193830f },
        { 0.01330370f, 0.05961421f, 0.09830813f },
        { 0.02193830f, 0.09830813f, 0.16210264f },
    };

    const v4f* Pb = &planeP[r0][tx];
    const v4f* Qb = &planeQ[r0][tx];

    // Centers j=0,1 at window offsets (2+j, 2).
    const v4f cP0 = Pb[2 * TP + 2], cQ0 = Qb[2 * TP + 2];
    const v4f cP1 = Pb[3 * TP + 2], cQ1 = Qb[3 * TP + 2];
    const v2f c2x0 = LOV(cP0) + LOV(cP0), c2y0 = HIV(cP0) + HIV(cP0);
    const v2f c2z0 = LOV(cQ0) + LOV(cQ0), cw0  = HIV(cQ0);
    const v2f c2x1 = LOV(cP1) + LOV(cP1), c2y1 = HIV(cP1) + HIV(cP1);
    const v2f c2z1 = LOV(cQ1) + LOV(cQ1), cw1  = HIV(cQ1);

    v2f nx0 = (v2f){0.f,0.f}, ny0 = nx0, nz0 = nx0, nd0 = nx0;
    v2f nx1 = nx0, ny1 = nx0, nz1 = nx0, nd1 = nx0;

#define TAP(c2x, c2y, c2z, cw, WK, nx, ny, nz, nd)                         \
    do {                                                                   \
        v2f t = __builtin_elementwise_fma(sz, c2z, sw);                    \
        t = __builtin_elementwise_fma(sy, c2y, t);                         \
        t = __builtin_elementwise_fma(sx, c2x, t);                         \
        t = t + cw;                                                        \
        const v2f e = (v2f){ EXP2(t.x), EXP2(t.y) };                       \
        const v2f w = e * (v2f){ WK, WK };                                 \
        nx = __builtin_elementwise_fma(w, sx, nx);                         \
        ny = __builtin_elementwise_fma(w, sy, ny);                         \
        nz = __builtin_elementwise_fma(w, sz, nz);                         \
        nd = nd + w;                                                       \
    } while (0)

    #pragma unroll
    for (int r = 0; r < 6; ++r) {
        #pragma unroll
        for (int kh = 0; kh < 2; ++kh) {          // phase split: k 0..2 | 3..4
            const int kbeg = kh ? 3 : 0;
            const int kend = kh ? 5 : 3;
            #pragma unroll
            for (int k = kbeg; k < kend; ++k) {
                const int ix = (k < 3) ? k : 4 - k;
                const v4f P = Pb[r * TP + k];
                const v4f Q = Qb[r * TP + k];
                const v2f sx = LOV(P), sy = HIV(P);
                const v2f sz = LOV(Q), sw = HIV(Q);
                if (r <= 4) {
                    const int iy = (r < 3) ? r : 4 - r;
                    TAP(c2x0, c2y0, c2z0, cw0, WKT[iy][ix], nx0, ny0, nz0, nd0);
                }
                if (r >= 1) {
                    const int dy = r - 1;
                    const int iy = (dy < 3) ? dy : 4 - dy;
                    TAP(c2x1, c2y1, c2z1, cw1, WKT[iy][ix], nx1, ny1, nz1, nd1);
                }
            }
            __builtin_amdgcn_sched_barrier(0);    // fence: cap live LDS loads
        }
    }
#undef TAP

    const int xcol = bx + tx;
    #pragma unroll
    for (int j = 0; j < 2; ++j) {
        const v2f nx = j ? nx1 : nx0, ny = j ? ny1 : ny0;
        const v2f nz = j ? nz1 : nz0, nd = j ? nd1 : nd0;
        {
            const float inv = RCP(nd.x * S);
            float* dst = out + ((size_t)(b * IMG_H + by + r0 + j) * IMG_W + xcol) * CH;
            dst[0] = fminf(fmaxf(nx.x * inv, 0.0f), 1.0f);
            dst[1] = fminf(fmaxf(ny.x * inv, 0.0f), 1.0f);
            dst[2] = fminf(fmaxf(nz.x * inv, 0.0f), 1.0f);
        }
        {
            const float inv = RCP(nd.y * S);
            float* dst = out + ((size_t)(b * IMG_H + by + HALF + r0 + j) * IMG_W + xcol) * CH;
            dst[0] = fminf(fmaxf(nx.y * inv, 0.0f), 1.0f);
            dst[1] = fminf(fmaxf(ny.y * inv, 0.0f), 1.0f);
            dst[2] = fminf(fmaxf(nz.y * inv, 0.0f), 1.0f);
        }
    }
}

extern "C" void kernel_launch(void* const* d_in, const int* in_sizes, int n_in,
                              void* d_out, int out_size, void* d_ws, size_t ws_size,
                              hipStream_t stream) {
    const float* in = (const float*)d_in[0];
    float* out = (float*)d_out;
    const int B = in_sizes[0] / (IMG_H * IMG_W * CH);   // 16

    dim3 block(TILE_W, 8, 1);
    dim3 grid(IMG_W / TILE_W, IMG_H / TILE_H, B);       // 32 x 16 x 16
    bilateral_kernel<<<grid, block, 0, stream>>>(in, out);
}

// Round 15
// 39.224 us; speedup vs baseline: 1.8496x; 1.8496x over previous
//
#include <hip/hip_runtime.h>
#include <hip/hip_fp16.h>
#include <math.h>

#define IMG_H 512
#define IMG_W 512
#define CH    3
#define TILE_W 16
#define TILE_H 64                // four 16-row quarters (A,B,C,D)
#define QTR   16
#define PAD   2
#define TP    20                 // padded per-quarter tile: 20 rows x 20 cols

#if __has_builtin(__builtin_amdgcn_rcpf)
#define RCP(x) __builtin_amdgcn_rcpf(x)
#else
#define RCP(x) (1.0f / (x))
#endif

__device__ __forceinline__ int reflect_idx(int i, int n) {
    i = (i < 0) ? -i : i;
    i = (i >= n) ? (2 * n - 2 - i) : i;
    return i;
}

__device__ __forceinline__ __half2 bch(unsigned int u) {
    return __builtin_bit_cast(__half2, u);
}
__device__ __forceinline__ unsigned int hcb(__half2 h) {
    return __builtin_bit_cast(unsigned int, h);
}

__global__ __launch_bounds__(256)
void bilateral_kernel(const float* __restrict__ in, float* __restrict__ out) {
    // 4 px/thread: same column, rows r, r+16, r+32, r+48 (quarters A..D),
    // channels f16-quantized and quad-interleaved:
    //   H4[r][c] = (x_AB, x_CD, y_AB, y_CD)   (uint4 of half2 -> ds_read_b128)
    //   H2[r][c] = (z_AB, z_CD)               (uint2 of half2 -> ds_read_b64)
    // One b128+b64 per tap serves 4 pixels (6 B/px/tap vs f32's 16).
    // NUMERICS: direct-difference form d2 = ||s-c||^2 in f16 — no large-value
    // cancellation (center tap exact); weight rel-err <1% where weights matter.
    // Stride 20 entries/row + wave lane-groups on rows 4 apart (rp permutation)
    // = the R3/R6/R12-proven conflict-free LDS geometry.
    __shared__ uint4 H4[TP][TP];   // 6.4 KB
    __shared__ uint2 H2[TP][TP];   // 3.2 KB

    const int b  = blockIdx.z;
    const int by = blockIdx.y * TILE_H;
    const int bx = blockIdx.x * TILE_W;
    const int tx = threadIdx.x;
    const int ty = threadIdx.y;
    const int tid = ty * TILE_W + tx;

    // Staging: 400 entries, each covers 4 pixels (quarters A..D).
    for (int i = tid; i < TP * TP; i += 256) {
        const int r  = i / TP;
        const int cc = i - r * TP;
        const int gx  = reflect_idx(bx + cc - PAD, IMG_W);
        const int gyA = reflect_idx(by + r - PAD, IMG_H);
        const int gyB = reflect_idx(by + QTR + r - PAD, IMG_H);
        const int gyC = reflect_idx(by + 2 * QTR + r - PAD, IMG_H);
        const int gyD = reflect_idx(by + 3 * QTR + r - PAD, IMG_H);
        const float* pA = in + ((size_t)(b * IMG_H + gyA) * IMG_W + gx) * CH;
        const float* pB = in + ((size_t)(b * IMG_H + gyB) * IMG_W + gx) * CH;
        const float* pC = in + ((size_t)(b * IMG_H + gyC) * IMG_W + gx) * CH;
        const float* pD = in + ((size_t)(b * IMG_H + gyD) * IMG_W + gx) * CH;
        uint4 h4;
        uint2 h2;
        h4.x = hcb(__floats2half2_rn(pA[0], pB[0]));
        h4.y = hcb(__floats2half2_rn(pC[0], pD[0]));
        h4.z = hcb(__floats2half2_rn(pA[1], pB[1]));
        h4.w = hcb(__floats2half2_rn(pC[1], pD[1]));
        h2.x = hcb(__floats2half2_rn(pA[2], pB[2]));
        h2.y = hcb(__floats2half2_rn(pC[2], pD[2]));
        H4[r][cc] = h4;
        H2[r][cc] = h2;
    }
    __syncthreads();

    // Row permutation: ty 0..3 -> rows 0,4,8,12 within each wave (conflict-free).
    const int rp = ((ty & 3) << 2) | (ty >> 2);

    // arg = K2 * d2 + log2(spatial): K2 = -log2(e)/(2*0.04^2) = -450.8422.
    const __half2 K2 = __float2half2_rn(-450.8422f);
    // log2 of normalized spatial products, index [min(dy,4-dy)][min(dx,4-dx)].
    const __half2 B2[3][3] = {
        { __float2half2_rn(-8.395800f), __float2half2_rn(-6.231757f), __float2half2_rn(-5.510409f) },
        { __float2half2_rn(-6.231757f), __float2half2_rn(-4.067714f), __float2half2_rn(-3.346367f) },
        { __float2half2_rn(-5.510409f), __float2half2_rn(-3.346367f), __float2half2_rn(-2.625024f) },
    };

    const uint4 cP = H4[rp + PAD][tx + PAD];
    const uint2 cQ = H2[rp + PAD][tx + PAD];
    const __half2 cxAB = bch(cP.x), cxCD = bch(cP.y);
    const __half2 cyAB = bch(cP.z), cyCD = bch(cP.w);
    const __half2 czAB = bch(cQ.x), czCD = bch(cQ.y);

    const __half2 z2 = __float2half2_rn(0.0f);
    __half2 nxAB = z2, nyAB = z2, nzAB = z2, ndAB = z2;
    __half2 nxCD = z2, nyCD = z2, nzCD = z2, ndCD = z2;

    #pragma unroll
    for (int dy = 0; dy < 5; ++dy) {
        const int iy = (dy < 3) ? dy : 4 - dy;
        #pragma unroll
        for (int k = 0; k < 5; ++k) {
            const int ix = (k < 3) ? k : 4 - k;
            const uint4 P = H4[rp + dy][tx + k];
            const uint2 Q = H2[rp + dy][tx + k];
            const __half2 sxAB = bch(P.x), sxCD = bch(P.y);
            const __half2 syAB = bch(P.z), syCD = bch(P.w);
            const __half2 szAB = bch(Q.x), szCD = bch(Q.y);
            // AB stream
            {
                const __half2 dx = __hsub2(sxAB, cxAB);
                const __half2 dyh = __hsub2(syAB, cyAB);
                const __half2 dz = __hsub2(szAB, czAB);
                const __half2 d2 = __hfma2(dx, dx, __hfma2(dyh, dyh, __hmul2(dz, dz)));
                const __half2 arg = __hfma2(d2, K2, B2[iy][ix]);
                const __half2 w = h2exp2(arg);
                nxAB = __hfma2(w, sxAB, nxAB);
                nyAB = __hfma2(w, syAB, nyAB);
                nzAB = __hfma2(w, szAB, nzAB);
                ndAB = __hadd2(ndAB, w);
            }
            // CD stream
            {
                const __half2 dx = __hsub2(sxCD, cxCD);
                const __half2 dyh = __hsub2(syCD, cyCD);
                const __half2 dz = __hsub2(szCD, czCD);
                const __half2 d2 = __hfma2(dx, dx, __hfma2(dyh, dyh, __hmul2(dz, dz)));
                const __half2 arg = __hfma2(d2, K2, B2[iy][ix]);
                const __half2 w = h2exp2(arg);
                nxCD = __hfma2(w, sxCD, nxCD);
                nyCD = __hfma2(w, syCD, nyCD);
                nzCD = __hfma2(w, szCD, nzCD);
                ndCD = __hadd2(ndCD, w);
            }
        }
    }

    const int xcol = bx + tx;
    #pragma unroll
    for (int q = 0; q < 4; ++q) {
        float n0, n1, n2, den;
        if (q == 0) { n0 = __low2float(nxAB);  n1 = __low2float(nyAB);  n2 = __low2float(nzAB);  den = __low2float(ndAB); }
        else if (q == 1) { n0 = __high2float(nxAB); n1 = __high2float(nyAB); n2 = __high2float(nzAB); den = __high2float(ndAB); }
        else if (q == 2) { n0 = __low2float(nxCD);  n1 = __low2float(nyCD);  n2 = __low2float(nzCD);  den = __low2float(ndCD); }
        else { n0 = __high2float(nxCD); n1 = __high2float(nyCD); n2 = __high2float(nzCD); den = __high2float(ndCD); }
        const float inv = RCP(den);
        const int y = by + q * QTR + rp;
        float* dst = out + ((size_t)(b * IMG_H + y) * IMG_W + xcol) * CH;
        dst[0] = fminf(fmaxf(n0 * inv, 0.0f), 1.0f);
        dst[1] = fminf(fmaxf(n1 * inv, 0.0f), 1.0f);
        dst[2] = fminf(fmaxf(n2 * inv, 0.0f), 1.0f);
    }
}

extern "C" void kernel_launch(void* const* d_in, const int* in_sizes, int n_in,
                              void* d_out, int out_size, void* d_ws, size_t ws_size,
                              hipStream_t stream) {
    const float* in = (const float*)d_in[0];
    float* out = (float*)d_out;
    const int B = in_sizes[0] / (IMG_H * IMG_W * CH);   // 16

    dim3 block(TILE_W, 16, 1);
    dim3 grid(IMG_W / TILE_W, IMG_H / TILE_H, B);       // 32 x 8 x 16
    bilateral_kernel<<<grid, block, 0, stream>>>(in, out);
}